// Round 2
// baseline (1224.928 us; speedup 1.0000x reference)
//
#include <hip/hip_runtime.h>
#include <stdint.h>

#define N_NODES 50000
#define N_EDGES 800000

typedef unsigned int uint32;

// ---------- bf16 helpers ----------
__device__ inline float bflo(uint32 u) { return __builtin_bit_cast(float, u << 16); }
__device__ inline float bfhi(uint32 u) { return __builtin_bit_cast(float, u & 0xffff0000u); }
__device__ inline float bf2f(unsigned short h) { return __builtin_bit_cast(float, (uint32)h << 16); }
__device__ inline unsigned short f2bf(float f) {
    uint32 u = __builtin_bit_cast(uint32, f);
    u += 0x7fffu + ((u >> 16) & 1u);  // RNE
    return (unsigned short)(u >> 16);
}
__device__ inline uint32 pack2(float lo, float hi) {
    return (uint32)f2bf(lo) | ((uint32)f2bf(hi) << 16);
}

// ---------- CSR build ----------
__global__ __launch_bounds__(256) void zero_k(int* p, int n) {
    int i = blockIdx.x * 256 + threadIdx.x;
    if (i < n) p[i] = 0;
}

__global__ __launch_bounds__(256) void count_k(const int* __restrict__ ei, int* __restrict__ cnt) {
    int e = blockIdx.x * 256 + threadIdx.x;
    if (e < N_EDGES) atomicAdd(&cnt[ei[N_EDGES + e]], 1);
}

#define NB 196  // 196*256 = 50176 >= 50000

__global__ __launch_bounds__(256) void blocksum_k(const int* __restrict__ cnt, int* __restrict__ bsum) {
    int i = blockIdx.x * 256 + threadIdx.x;
    int v = (i < N_NODES) ? cnt[i] : 0;
#pragma unroll
    for (int off = 32; off > 0; off >>= 1) v += __shfl_down(v, off);
    __shared__ int sh[4];
    int w = threadIdx.x >> 6, lane = threadIdx.x & 63;
    if (lane == 0) sh[w] = v;
    __syncthreads();
    if (threadIdx.x == 0) bsum[blockIdx.x] = sh[0] + sh[1] + sh[2] + sh[3];
}

__global__ __launch_bounds__(256) void bscan_k(const int* __restrict__ bsum, int* __restrict__ bpre,
                                               int* __restrict__ rowptr) {
    __shared__ int sh[256];
    int t = threadIdx.x;
    int v = (t < NB) ? bsum[t] : 0;
    sh[t] = v;
    __syncthreads();
    for (int d = 1; d < 256; d <<= 1) {
        int u = (t >= d) ? sh[t - d] : 0;
        __syncthreads();
        sh[t] += u;
        __syncthreads();
    }
    if (t < NB) bpre[t] = sh[t] - v;          // exclusive block prefix
    if (t == NB - 1) rowptr[N_NODES] = sh[t]; // total = N_EDGES
}

__global__ __launch_bounds__(256) void scatter_k(int* __restrict__ cnt, const int* __restrict__ bpre,
                                                 int* __restrict__ rowptr) {
    int b = blockIdx.x, t = threadIdx.x, i = b * 256 + t;
    int w = t >> 6, lane = t & 63;
    int myv = (i < N_NODES) ? cnt[i] : 0;
    int v = myv;
#pragma unroll
    for (int d = 1; d < 64; d <<= 1) {
        int u = __shfl_up(v, d);
        if (lane >= d) v += u;
    }
    __shared__ int wt[4];
    if (lane == 63) wt[w] = v;
    __syncthreads();
    int off = bpre[b];
    for (int k = 0; k < w; k++) off += wt[k];
    int excl = v - myv + off;
    if (i < N_NODES) {
        rowptr[i] = excl;
        cnt[i] = excl;  // becomes cursor
    }
}

__global__ __launch_bounds__(256) void fill_k(const int* __restrict__ ei, int* __restrict__ cursor,
                                              int* __restrict__ csr) {
    int e = blockIdx.x * 256 + threadIdx.x;
    if (e < N_EDGES) {
        int d = ei[N_EDGES + e];
        int p = atomicAdd(&cursor[d], 1);
        csr[p] = ei[e];  // src
    }
}

// ---------- weight prep: W fp32 [k][n] -> Whi/Wlo bf16 [n][k], LDS-tiled transpose ----------
__global__ __launch_bounds__(256) void wprep_k(const float* __restrict__ W,
                                               unsigned short* __restrict__ Whi,
                                               unsigned short* __restrict__ Wlo) {
    __shared__ float sh[64][65];  // +1 pad
    int bk = (blockIdx.x & 7) * 64;
    int bn = (blockIdx.x >> 3) * 64;
    int t = threadIdx.x;
    int lr = t >> 4;         // 0..15
    int lc4 = (t & 15) * 4;  // 0,4,..,60
#pragma unroll
    for (int i = 0; i < 4; i++) {
        int k = lr + i * 16;
        float4 v = *(const float4*)&W[(size_t)(bk + k) * 512 + bn + lc4];
        sh[k][lc4] = v.x; sh[k][lc4 + 1] = v.y; sh[k][lc4 + 2] = v.z; sh[k][lc4 + 3] = v.w;
    }
    __syncthreads();
#pragma unroll
    for (int i = 0; i < 4; i++) {
        int n = lr + i * 16;
        float w0 = sh[lc4][n], w1 = sh[lc4 + 1][n], w2 = sh[lc4 + 2][n], w3 = sh[lc4 + 3][n];
        ushort4 h, l;
        h.x = f2bf(w0); l.x = f2bf(w0 - bf2f(h.x));
        h.y = f2bf(w1); l.y = f2bf(w1 - bf2f(h.y));
        h.z = f2bf(w2); l.z = f2bf(w2 - bf2f(h.z));
        h.w = f2bf(w3); l.w = f2bf(w3 - bf2f(h.w));
        *(ushort4*)&Whi[(size_t)(bn + n) * 512 + bk + lc4] = h;
        *(ushort4*)&Wlo[(size_t)(bn + n) * 512 + bk + lc4] = l;
    }
}

// ---------- x fp32 -> bf16 packed (float4 -> uint2) ----------
__global__ __launch_bounds__(256) void xconv_k(const float4* __restrict__ x, uint2* __restrict__ xb) {
    int i = blockIdx.x * 256 + threadIdx.x;  // 6.4M
    float4 v = x[i];
    uint2 o;
    o.x = pack2(v.x, v.y);
    o.y = pack2(v.z, v.w);
    xb[i] = o;
}

// ---------- ss -> inverse norm ----------
__global__ __launch_bounds__(256) void invn_k(const float* __restrict__ ss, float* __restrict__ invn) {
    int i = blockIdx.x * 256 + threadIdx.x;
    if (i < N_NODES) invn[i] = 1.0f / fmaxf(sqrtf(ss[i]), 1e-12f);
}

// ---------- fused GIN layer: gather(agg, L2-normalized) -> LDS A-tile -> MFMA GEMM -> epilogue ----------
// Block: 512 threads = 8 waves. TM=32 dst rows, full N=512 (no N-tiling -> gather happens once).
// Wave w gathers rows w*4..w*4+3 into a 32KB XOR-swizzled LDS tile, then computes its private
// 32x64 output slice with B fragments loaded directly from global (W is L2-resident).
typedef __bf16 bf16x8 __attribute__((ext_vector_type(8)));
typedef float f32x4 __attribute__((ext_vector_type(4)));

template <bool SCALED, bool SPLIT, bool F32OUT, bool NORM>
__global__ __launch_bounds__(512, 4) void fused_k(const uint4* __restrict__ xin,
                                                  const int* __restrict__ rowptr,
                                                  const int* __restrict__ csr,
                                                  const float* __restrict__ eps,
                                                  const float* __restrict__ invn,
                                                  const unsigned short* __restrict__ Whi,
                                                  const unsigned short* __restrict__ Wlo,
                                                  const float* __restrict__ bias,
                                                  unsigned short* __restrict__ outB,
                                                  float* __restrict__ outF,
                                                  float* __restrict__ ssOut) {
    constexpr int K = 512, N = 512, TM = 32;
    __shared__ unsigned short lds_a[TM * K];  // 32 KB
    const int t = threadIdx.x;
    const int w = t >> 6, lane = t & 63;
    const int m0 = blockIdx.x * TM;

    // ---- gather phase: wave w builds A-tile rows w*4 .. w*4+3 ----
    for (int rr = 0; rr < 4; ++rr) {
        int row = w * 4 + rr;
        int node = m0 + row;
        float a0 = 0.f, a1 = 0.f, a2 = 0.f, a3 = 0.f, a4 = 0.f, a5 = 0.f, a6 = 0.f, a7 = 0.f;
        if (node < N_NODES) {
            int beg = rowptr[node], end = rowptr[node + 1];
            int e = beg;
            for (; e + 4 <= end; e += 4) {
                int s0 = csr[e], s1 = csr[e + 1], s2 = csr[e + 2], s3 = csr[e + 3];
                uint4 q0 = xin[(size_t)s0 * 64 + lane];
                uint4 q1 = xin[(size_t)s1 * 64 + lane];
                uint4 q2 = xin[(size_t)s2 * 64 + lane];
                uint4 q3 = xin[(size_t)s3 * 64 + lane];
                float w0 = SCALED ? invn[s0] : 1.0f;
                float w1 = SCALED ? invn[s1] : 1.0f;
                float w2 = SCALED ? invn[s2] : 1.0f;
                float w3 = SCALED ? invn[s3] : 1.0f;
                a0 = fmaf(w0, bflo(q0.x), fmaf(w1, bflo(q1.x), fmaf(w2, bflo(q2.x), fmaf(w3, bflo(q3.x), a0))));
                a1 = fmaf(w0, bfhi(q0.x), fmaf(w1, bfhi(q1.x), fmaf(w2, bfhi(q2.x), fmaf(w3, bfhi(q3.x), a1))));
                a2 = fmaf(w0, bflo(q0.y), fmaf(w1, bflo(q1.y), fmaf(w2, bflo(q2.y), fmaf(w3, bflo(q3.y), a2))));
                a3 = fmaf(w0, bfhi(q0.y), fmaf(w1, bfhi(q1.y), fmaf(w2, bfhi(q2.y), fmaf(w3, bfhi(q3.y), a3))));
                a4 = fmaf(w0, bflo(q0.z), fmaf(w1, bflo(q1.z), fmaf(w2, bflo(q2.z), fmaf(w3, bflo(q3.z), a4))));
                a5 = fmaf(w0, bfhi(q0.z), fmaf(w1, bfhi(q1.z), fmaf(w2, bfhi(q2.z), fmaf(w3, bfhi(q3.z), a5))));
                a6 = fmaf(w0, bflo(q0.w), fmaf(w1, bflo(q1.w), fmaf(w2, bflo(q2.w), fmaf(w3, bflo(q3.w), a6))));
                a7 = fmaf(w0, bfhi(q0.w), fmaf(w1, bfhi(q1.w), fmaf(w2, bfhi(q2.w), fmaf(w3, bfhi(q3.w), a7))));
            }
            for (; e < end; ++e) {
                int s0 = csr[e];
                uint4 q0 = xin[(size_t)s0 * 64 + lane];
                float w0 = SCALED ? invn[s0] : 1.0f;
                a0 = fmaf(w0, bflo(q0.x), a0); a1 = fmaf(w0, bfhi(q0.x), a1);
                a2 = fmaf(w0, bflo(q0.y), a2); a3 = fmaf(w0, bfhi(q0.y), a3);
                a4 = fmaf(w0, bflo(q0.z), a4); a5 = fmaf(w0, bfhi(q0.z), a5);
                a6 = fmaf(w0, bflo(q0.w), a6); a7 = fmaf(w0, bfhi(q0.w), a7);
            }
            uint4 qs = xin[(size_t)node * 64 + lane];
            float wsf = (1.0f + eps[0]) * (SCALED ? invn[node] : 1.0f);
            a0 = fmaf(wsf, bflo(qs.x), a0); a1 = fmaf(wsf, bfhi(qs.x), a1);
            a2 = fmaf(wsf, bflo(qs.y), a2); a3 = fmaf(wsf, bfhi(qs.y), a3);
            a4 = fmaf(wsf, bflo(qs.z), a4); a5 = fmaf(wsf, bfhi(qs.z), a5);
            a6 = fmaf(wsf, bflo(qs.w), a6); a7 = fmaf(wsf, bfhi(qs.w), a7);
        }
        uint4 o;
        o.x = pack2(a0, a1);
        o.y = pack2(a2, a3);
        o.z = pack2(a4, a5);
        o.w = pack2(a6, a7);
        // XOR-swizzled LDS store (breaks the 1KB-stride bank conflict on MFMA-fragment reads)
        uint32 byte = (uint32)(row * 1024 + lane * 16) ^ (uint32)((row & 7) << 4);
        *(uint4*)((char*)lds_a + byte) = o;
    }
    __syncthreads();

    // ---- GEMM phase: wave w computes rows m0..m0+31, cols w*64..w*64+63 ----
    const int quad = lane >> 4, l15 = lane & 15;
    const int n0w = w * 64;
    const uint32 swz = (uint32)((l15 & 7) << 4);
    f32x4 acc[2][4] = {};
    const unsigned short* bh[4];
    const unsigned short* bl[4];
#pragma unroll
    for (int j = 0; j < 4; j++) {
        bh[j] = Whi + (size_t)(n0w + j * 16 + l15) * K + quad * 8;
        if (SPLIT) bl[j] = Wlo + (size_t)(n0w + j * 16 + l15) * K + quad * 8;
    }
#pragma unroll 4
    for (int ks = 0; ks < 16; ++ks) {
        const int k0 = ks * 32;
        bf16x8 af[2];
#pragma unroll
        for (int i = 0; i < 2; i++) {
            uint32 byte = (uint32)((i * 16 + l15) * 1024 + (k0 + quad * 8) * 2) ^ swz;
            af[i] = *(const bf16x8*)((const char*)lds_a + byte);
        }
#pragma unroll
        for (int j = 0; j < 4; j++) {
            bf16x8 b = *(const bf16x8*)(bh[j] + k0);
            acc[0][j] = __builtin_amdgcn_mfma_f32_16x16x32_bf16(af[0], b, acc[0][j], 0, 0, 0);
            acc[1][j] = __builtin_amdgcn_mfma_f32_16x16x32_bf16(af[1], b, acc[1][j], 0, 0, 0);
        }
        if (SPLIT) {
#pragma unroll
            for (int j = 0; j < 4; j++) {
                bf16x8 b = *(const bf16x8*)(bl[j] + k0);
                acc[0][j] = __builtin_amdgcn_mfma_f32_16x16x32_bf16(af[0], b, acc[0][j], 0, 0, 0);
                acc[1][j] = __builtin_amdgcn_mfma_f32_16x16x32_bf16(af[1], b, acc[1][j], 0, 0, 0);
            }
        }
    }

    // ---- epilogue: bias + relu (+fused row sum-of-squares) ----
#pragma unroll
    for (int i = 0; i < 2; i++) {
        int mbase = m0 + i * 16 + quad * 4;
        float rs[4] = {0.f, 0.f, 0.f, 0.f};
#pragma unroll
        for (int j = 0; j < 4; j++) {
            int n = n0w + j * 16 + l15;
            float bv = bias[n];
#pragma unroll
            for (int r = 0; r < 4; r++) {
                int m = mbase + r;
                if (m < N_NODES) {
                    float v = fmaxf(acc[i][j][r] + bv, 0.0f);
                    if (NORM) rs[r] += v * v;
                    if (F32OUT) outF[(size_t)m * N + n] = v;
                    else        outB[(size_t)m * N + n] = f2bf(v);
                }
            }
        }
        if (NORM) {
#pragma unroll
            for (int r = 0; r < 4; r++) {
                float s = rs[r];
                s += __shfl_xor(s, 1);
                s += __shfl_xor(s, 2);
                s += __shfl_xor(s, 4);
                s += __shfl_xor(s, 8);
                int m = mbase + r;
                if (l15 == 0 && m < N_NODES) atomicAdd(&ssOut[m], s);
            }
        }
    }
}

// ---------- softmax over 512 classes (fp32) ----------
__global__ __launch_bounds__(256) void softmax_k(const float* __restrict__ logits,
                                                 float* __restrict__ probs) {
    int node = blockIdx.x * 4 + (threadIdx.x >> 6);
    int lane = threadIdx.x & 63;
    const float4* zp = (const float4*)(logits + (size_t)node * 512);
    float4 q0 = zp[lane * 2], q1 = zp[lane * 2 + 1];
    float f[8] = {q0.x, q0.y, q0.z, q0.w, q1.x, q1.y, q1.z, q1.w};
    float m = f[0];
#pragma unroll
    for (int i = 1; i < 8; i++) m = fmaxf(m, f[i]);
#pragma unroll
    for (int off = 32; off > 0; off >>= 1) m = fmaxf(m, __shfl_xor(m, off));
    float e[8], s = 0.f;
#pragma unroll
    for (int i = 0; i < 8; i++) { e[i] = __expf(f[i] - m); s += e[i]; }
#pragma unroll
    for (int off = 32; off > 0; off >>= 1) s += __shfl_xor(s, off);
    float inv = 1.0f / s;
    float4* pp = (float4*)(probs + (size_t)node * 512);
    pp[lane * 2]     = make_float4(e[0] * inv, e[1] * inv, e[2] * inv, e[3] * inv);
    pp[lane * 2 + 1] = make_float4(e[4] * inv, e[5] * inv, e[6] * inv, e[7] * inv);
}

// ---------- host launch ----------
extern "C" void kernel_launch(void* const* d_in, const int* in_sizes, int n_in,
                              void* d_out, int out_size, void* d_ws, size_t ws_size,
                              hipStream_t stream) {
    (void)in_sizes; (void)n_in; (void)out_size; (void)ws_size;
    const float* x = (const float*)d_in[0];
    const int* ei = (const int*)d_in[1];
    const float* W1 = (const float*)d_in[2];
    const float* b1 = (const float*)d_in[3];
    const float* e1 = (const float*)d_in[4];
    const float* W2 = (const float*)d_in[5];
    const float* b2 = (const float*)d_in[6];
    const float* e2 = (const float*)d_in[7];
    const float* W3 = (const float*)d_in[8];
    const float* b3 = (const float*)d_in[9];
    const float* e3 = (const float*)d_in[10];
    float* out = (float*)d_out;
    float* out_logits = out;
    float* out_probs = out + (size_t)N_NODES * 512;

    // workspace layout (~110 MB)
    char* ws = (char*)d_ws;
    int* rowptr = (int*)ws;                          // 50048 ints
    int* cursor = rowptr + 50048;                    // 50048 ints
    int* csr = cursor + 50048;                       // 800000 ints
    float* invn = (float*)(csr + N_EDGES);           // 50048 floats
    int* bsum = (int*)(invn + 50048);                // 256 ints
    int* bpre = bsum + 256;                          // 256 ints
    float* ss = (float*)(bpre + 256);                // 2*50048 floats
    float* ss1 = ss;
    float* ss2 = ss + 50048;
    unsigned short* Wsp = (unsigned short*)(ss + 2 * 50048);
    unsigned short* fy = Wsp + 3 * 524288;           // feature ping (51.2 MB)
    unsigned short* fx = fy + (size_t)N_NODES * 512; // feature pong (51.2 MB)

    // CSR build + ss zero
    zero_k<<<196, 256, 0, stream>>>(cursor, N_NODES);
    zero_k<<<392, 256, 0, stream>>>((int*)ss, 2 * 50048);
    count_k<<<(N_EDGES + 255) / 256, 256, 0, stream>>>(ei, cursor);
    blocksum_k<<<NB, 256, 0, stream>>>(cursor, bsum);
    bscan_k<<<1, 256, 0, stream>>>(bsum, bpre, rowptr);
    scatter_k<<<NB, 256, 0, stream>>>(cursor, bpre, rowptr);
    fill_k<<<(N_EDGES + 255) / 256, 256, 0, stream>>>(ei, cursor, csr);

    // weight prep (hi/lo bf16, transposed to [n][k])
    wprep_k<<<64, 256, 0, stream>>>(W1, Wsp,           Wsp + 262144);
    wprep_k<<<64, 256, 0, stream>>>(W2, Wsp + 524288,  Wsp + 786432);
    wprep_k<<<64, 256, 0, stream>>>(W3, Wsp + 1048576, Wsp + 1310720);

    // x -> bf16
    xconv_k<<<25000, 256, 0, stream>>>((const float4*)x, (uint2*)fx);

    const int FG = (N_NODES + 31) / 32;  // 1563 blocks

    // layer 1: in fx -> out fy, fused ss1
    fused_k<false, false, false, true><<<FG, 512, 0, stream>>>(
        (const uint4*)fx, rowptr, csr, e1, nullptr, Wsp, nullptr, b1, fy, nullptr, ss1);
    invn_k<<<196, 256, 0, stream>>>(ss1, invn);
    // layer 2: in fy -> out fx, fused ss2
    fused_k<true, false, false, true><<<FG, 512, 0, stream>>>(
        (const uint4*)fy, rowptr, csr, e2, invn, Wsp + 524288, nullptr, b2, fx, nullptr, ss2);
    invn_k<<<196, 256, 0, stream>>>(ss2, invn);
    // layer 3: in fx -> fp32 logits (split-precision W3)
    fused_k<true, true, true, false><<<FG, 512, 0, stream>>>(
        (const uint4*)fx, rowptr, csr, e3, invn, Wsp + 1048576, Wsp + 1310720, b3, nullptr, out_logits, nullptr);
    // softmax -> probs
    softmax_k<<<N_NODES / 4, 256, 0, stream>>>(out_logits, out_probs);
}

// Round 3
// 1003.692 us; speedup vs baseline: 1.2204x; 1.2204x over previous
//
#include <hip/hip_runtime.h>
#include <stdint.h>

#define N_NODES 50000
#define N_EDGES 800000

typedef unsigned int uint32;

// ---------- bf16 helpers ----------
__device__ inline float bflo(uint32 u) { return __builtin_bit_cast(float, u << 16); }
__device__ inline float bfhi(uint32 u) { return __builtin_bit_cast(float, u & 0xffff0000u); }
__device__ inline float bf2f(unsigned short h) { return __builtin_bit_cast(float, (uint32)h << 16); }
__device__ inline unsigned short f2bf(float f) {
    uint32 u = __builtin_bit_cast(uint32, f);
    u += 0x7fffu + ((u >> 16) & 1u);  // RNE
    return (unsigned short)(u >> 16);
}
__device__ inline uint32 pack2(float lo, float hi) {
    return (uint32)f2bf(lo) | ((uint32)f2bf(hi) << 16);
}

// ---------- CSR build ----------
__global__ __launch_bounds__(256) void zero_k(int* p, int n) {
    int i = blockIdx.x * 256 + threadIdx.x;
    if (i < n) p[i] = 0;
}

__global__ __launch_bounds__(256) void count_k(const int* __restrict__ ei, int* __restrict__ cnt) {
    int e = blockIdx.x * 256 + threadIdx.x;
    if (e < N_EDGES) atomicAdd(&cnt[ei[N_EDGES + e]], 1);
}

#define NB 196  // 196*256 = 50176 >= 50000

__global__ __launch_bounds__(256) void blocksum_k(const int* __restrict__ cnt, int* __restrict__ bsum) {
    int i = blockIdx.x * 256 + threadIdx.x;
    int v = (i < N_NODES) ? cnt[i] : 0;
#pragma unroll
    for (int off = 32; off > 0; off >>= 1) v += __shfl_down(v, off);
    __shared__ int sh[4];
    int w = threadIdx.x >> 6, lane = threadIdx.x & 63;
    if (lane == 0) sh[w] = v;
    __syncthreads();
    if (threadIdx.x == 0) bsum[blockIdx.x] = sh[0] + sh[1] + sh[2] + sh[3];
}

__global__ __launch_bounds__(256) void bscan_k(const int* __restrict__ bsum, int* __restrict__ bpre,
                                               int* __restrict__ rowptr) {
    __shared__ int sh[256];
    int t = threadIdx.x;
    int v = (t < NB) ? bsum[t] : 0;
    sh[t] = v;
    __syncthreads();
    for (int d = 1; d < 256; d <<= 1) {
        int u = (t >= d) ? sh[t - d] : 0;
        __syncthreads();
        sh[t] += u;
        __syncthreads();
    }
    if (t < NB) bpre[t] = sh[t] - v;          // exclusive block prefix
    if (t == NB - 1) rowptr[N_NODES] = sh[t]; // total = N_EDGES
}

__global__ __launch_bounds__(256) void scatter_k(int* __restrict__ cnt, const int* __restrict__ bpre,
                                                 int* __restrict__ rowptr) {
    int b = blockIdx.x, t = threadIdx.x, i = b * 256 + t;
    int w = t >> 6, lane = t & 63;
    int myv = (i < N_NODES) ? cnt[i] : 0;
    int v = myv;
#pragma unroll
    for (int d = 1; d < 64; d <<= 1) {
        int u = __shfl_up(v, d);
        if (lane >= d) v += u;
    }
    __shared__ int wt[4];
    if (lane == 63) wt[w] = v;
    __syncthreads();
    int off = bpre[b];
    for (int k = 0; k < w; k++) off += wt[k];
    int excl = v - myv + off;
    if (i < N_NODES) {
        rowptr[i] = excl;
        cnt[i] = excl;  // becomes cursor
    }
}

__global__ __launch_bounds__(256) void fill_k(const int* __restrict__ ei, int* __restrict__ cursor,
                                              int* __restrict__ csr) {
    int e = blockIdx.x * 256 + threadIdx.x;
    if (e < N_EDGES) {
        int d = ei[N_EDGES + e];
        int p = atomicAdd(&cursor[d], 1);
        csr[p] = ei[e];  // src
    }
}

// ---------- weight prep: W fp32 [k][n] -> Whi/Wlo bf16 [n][k], LDS-tiled transpose ----------
__global__ __launch_bounds__(256) void wprep_k(const float* __restrict__ W,
                                               unsigned short* __restrict__ Whi,
                                               unsigned short* __restrict__ Wlo) {
    __shared__ float sh[64][65];  // +1 pad
    int bk = (blockIdx.x & 7) * 64;
    int bn = (blockIdx.x >> 3) * 64;
    int t = threadIdx.x;
    int lr = t >> 4;         // 0..15
    int lc4 = (t & 15) * 4;  // 0,4,..,60
#pragma unroll
    for (int i = 0; i < 4; i++) {
        int k = lr + i * 16;
        float4 v = *(const float4*)&W[(size_t)(bk + k) * 512 + bn + lc4];
        sh[k][lc4] = v.x; sh[k][lc4 + 1] = v.y; sh[k][lc4 + 2] = v.z; sh[k][lc4 + 3] = v.w;
    }
    __syncthreads();
#pragma unroll
    for (int i = 0; i < 4; i++) {
        int n = lr + i * 16;
        float w0 = sh[lc4][n], w1 = sh[lc4 + 1][n], w2 = sh[lc4 + 2][n], w3 = sh[lc4 + 3][n];
        ushort4 h, l;
        h.x = f2bf(w0); l.x = f2bf(w0 - bf2f(h.x));
        h.y = f2bf(w1); l.y = f2bf(w1 - bf2f(h.y));
        h.z = f2bf(w2); l.z = f2bf(w2 - bf2f(h.z));
        h.w = f2bf(w3); l.w = f2bf(w3 - bf2f(h.w));
        *(ushort4*)&Whi[(size_t)(bn + n) * 512 + bk + lc4] = h;
        *(ushort4*)&Wlo[(size_t)(bn + n) * 512 + bk + lc4] = l;
    }
}

// ---------- x fp32 -> bf16 packed (float4 -> uint2) ----------
__global__ __launch_bounds__(256) void xconv_k(const float4* __restrict__ x, uint2* __restrict__ xb) {
    int i = blockIdx.x * 256 + threadIdx.x;  // 6.4M
    float4 v = x[i];
    uint2 o;
    o.x = pack2(v.x, v.y);
    o.y = pack2(v.z, v.w);
    xb[i] = o;
}

// ---------- per-node scale: out = in * (1/max(sqrt(ss),eps))  (= relu(l2norm(y)) for y>=0) ----------
__global__ __launch_bounds__(256) void scale_k(const uint4* __restrict__ in, const float* __restrict__ ss,
                                               uint4* __restrict__ outp) {
    int node = blockIdx.x * 4 + (threadIdx.x >> 6);
    int lane = threadIdx.x & 63;
    float inv = 1.0f / fmaxf(sqrtf(ss[node]), 1e-12f);
    uint4 q = in[(size_t)node * 64 + lane];
    uint4 o;
    o.x = pack2(bflo(q.x) * inv, bfhi(q.x) * inv);
    o.y = pack2(bflo(q.y) * inv, bfhi(q.y) * inv);
    o.z = pack2(bflo(q.z) * inv, bfhi(q.z) * inv);
    o.w = pack2(bflo(q.w) * inv, bfhi(q.w) * inv);
    outp[(size_t)node * 64 + lane] = o;
}

// ---------- aggregation: wave-per-node, pure-sum, unroll-8 for MLP ----------
#define ACC8(Q)                                                     \
    a0 += bflo(Q.x); a1 += bfhi(Q.x); a2 += bflo(Q.y); a3 += bfhi(Q.y); \
    a4 += bflo(Q.z); a5 += bfhi(Q.z); a6 += bflo(Q.w); a7 += bfhi(Q.w);

__global__ __launch_bounds__(256) void agg_k(const uint4* __restrict__ xin,
                                             const int* __restrict__ rowptr,
                                             const int* __restrict__ csr,
                                             const float* __restrict__ eps,
                                             uint4* __restrict__ hout) {
    int node = blockIdx.x * 4 + (threadIdx.x >> 6);
    int lane = threadIdx.x & 63;
    int beg = rowptr[node], end = rowptr[node + 1];
    float a0 = 0.f, a1 = 0.f, a2 = 0.f, a3 = 0.f, a4 = 0.f, a5 = 0.f, a6 = 0.f, a7 = 0.f;
    int e = beg;
    for (; e + 8 <= end; e += 8) {
        int s0 = csr[e],     s1 = csr[e + 1], s2 = csr[e + 2], s3 = csr[e + 3];
        int s4 = csr[e + 4], s5 = csr[e + 5], s6 = csr[e + 6], s7 = csr[e + 7];
        uint4 q0 = xin[(size_t)s0 * 64 + lane];
        uint4 q1 = xin[(size_t)s1 * 64 + lane];
        uint4 q2 = xin[(size_t)s2 * 64 + lane];
        uint4 q3 = xin[(size_t)s3 * 64 + lane];
        uint4 q4 = xin[(size_t)s4 * 64 + lane];
        uint4 q5 = xin[(size_t)s5 * 64 + lane];
        uint4 q6 = xin[(size_t)s6 * 64 + lane];
        uint4 q7 = xin[(size_t)s7 * 64 + lane];
        ACC8(q0) ACC8(q1) ACC8(q2) ACC8(q3)
        ACC8(q4) ACC8(q5) ACC8(q6) ACC8(q7)
    }
    for (; e + 4 <= end; e += 4) {
        int s0 = csr[e], s1 = csr[e + 1], s2 = csr[e + 2], s3 = csr[e + 3];
        uint4 q0 = xin[(size_t)s0 * 64 + lane];
        uint4 q1 = xin[(size_t)s1 * 64 + lane];
        uint4 q2 = xin[(size_t)s2 * 64 + lane];
        uint4 q3 = xin[(size_t)s3 * 64 + lane];
        ACC8(q0) ACC8(q1) ACC8(q2) ACC8(q3)
    }
    for (; e < end; ++e) {
        int s0 = csr[e];
        uint4 q0 = xin[(size_t)s0 * 64 + lane];
        ACC8(q0)
    }
    uint4 qs = xin[(size_t)node * 64 + lane];
    float ws = 1.0f + eps[0];
    a0 = fmaf(ws, bflo(qs.x), a0); a1 = fmaf(ws, bfhi(qs.x), a1);
    a2 = fmaf(ws, bflo(qs.y), a2); a3 = fmaf(ws, bfhi(qs.y), a3);
    a4 = fmaf(ws, bflo(qs.z), a4); a5 = fmaf(ws, bfhi(qs.z), a5);
    a6 = fmaf(ws, bflo(qs.w), a6); a7 = fmaf(ws, bfhi(qs.w), a7);
    uint4 o;
    o.x = pack2(a0, a1);
    o.y = pack2(a2, a3);
    o.z = pack2(a4, a5);
    o.w = pack2(a6, a7);
    hout[(size_t)node * 64 + lane] = o;
}

// ---------- GEMM: relu(A[M,512](bf16) @ W[512,512] + b(fp32)), fused row-sum-of-squares ----------
// 1D grid with bijective XCD-chunk swizzle (n-fastest within chunk) so the 4 n-blocks sharing an
// A m-tile run back-to-back on the SAME XCD -> A-tile served from that XCD's L2 (4x -> 1x fetch).
typedef __bf16 bf16x8 __attribute__((ext_vector_type(8)));
typedef float f32x4 __attribute__((ext_vector_type(4)));

__device__ inline void async16(const void* g, void* l) {
    __builtin_amdgcn_global_load_lds((const __attribute__((address_space(1))) void*)g,
                                     (__attribute__((address_space(3))) void*)l, 16, 0, 0);
}

template <bool SPLIT, bool F32OUT, bool NORM>
__global__ __launch_bounds__(256) void gemm_k(const unsigned short* __restrict__ A,
                                              const unsigned short* __restrict__ Whi,
                                              const unsigned short* __restrict__ Wlo,
                                              const float* __restrict__ bias,
                                              unsigned short* __restrict__ outB,
                                              float* __restrict__ outF,
                                              float* __restrict__ ssOut, int M) {
    constexpr int K = 512, N = 512, BK = 32, TM = 128;
    __shared__ unsigned short lds_a[TM * BK];
    __shared__ unsigned short lds_bh[TM * BK];
    __shared__ unsigned short lds_bl[SPLIT ? TM * BK : 16];
    const int t = threadIdx.x;
    const int w = t >> 6, lane = t & 63;
    const int wrow = w >> 1, wcol = w & 1;

    // bijective XCD swizzle: xcd = bid%8 gets a contiguous chunk of wg-space
    const int nwg = gridDim.x;
    const int qd = nwg >> 3, rd = nwg & 7;
    const int xcd = blockIdx.x & 7, jj = blockIdx.x >> 3;
    const int wg = (xcd < rd ? xcd * (qd + 1) : rd * (qd + 1) + (xcd - rd) * qd) + jj;
    const int m0 = (wg >> 2) * TM;  // n-fastest: same-m blocks adjacent on same XCD
    const int n0 = (wg & 3) * TM;

    int r0 = w * 16 + (lane >> 2), cc = (lane & 3) * 8;
    int r1 = 64 + r0;
    int am0 = m0 + r0; am0 = am0 < M ? am0 : M - 1;
    int am1 = m0 + r1; am1 = am1 < M ? am1 : M - 1;
    const unsigned short* ag0 = A + (size_t)am0 * K + cc;
    const unsigned short* ag1 = A + (size_t)am1 * K + cc;
    const unsigned short* bh0 = Whi + (size_t)(n0 + r0) * K + cc;
    const unsigned short* bh1 = Whi + (size_t)(n0 + r1) * K + cc;
    const unsigned short* bl0 = Wlo + (size_t)(n0 + r0) * K + cc;
    const unsigned short* bl1 = Wlo + (size_t)(n0 + r1) * K + cc;
    unsigned short* la0 = lds_a + w * 512;
    unsigned short* la1 = lds_a + 2048 + w * 512;
    unsigned short* lh0 = lds_bh + w * 512;
    unsigned short* lh1 = lds_bh + 2048 + w * 512;
    unsigned short* ll0 = lds_bl + w * 512;
    unsigned short* ll1 = lds_bl + 2048 + w * 512;

    f32x4 acc[4][4] = {};
    const int quad = lane >> 4, l15 = lane & 15;
    const int arow = wrow * 64 + l15;
    const int brow = wcol * 64 + l15;

    for (int k0 = 0; k0 < K; k0 += BK) {
        __syncthreads();
        async16(ag0 + k0, la0);
        async16(ag1 + k0, la1);
        async16(bh0 + k0, lh0);
        async16(bh1 + k0, lh1);
        if (SPLIT) {
            async16(bl0 + k0, ll0);
            async16(bl1 + k0, ll1);
        }
        __syncthreads();
        bf16x8 af[4], bh[4], bl[4];
#pragma unroll
        for (int i = 0; i < 4; i++)
            af[i] = *(const bf16x8*)&lds_a[(arow + i * 16) * BK + quad * 8];
#pragma unroll
        for (int j = 0; j < 4; j++)
            bh[j] = *(const bf16x8*)&lds_bh[(brow + j * 16) * BK + quad * 8];
        if (SPLIT) {
#pragma unroll
            for (int j = 0; j < 4; j++)
                bl[j] = *(const bf16x8*)&lds_bl[(brow + j * 16) * BK + quad * 8];
        }
#pragma unroll
        for (int i = 0; i < 4; i++)
#pragma unroll
            for (int j = 0; j < 4; j++) {
                acc[i][j] = __builtin_amdgcn_mfma_f32_16x16x32_bf16(af[i], bh[j], acc[i][j], 0, 0, 0);
                if (SPLIT)
                    acc[i][j] = __builtin_amdgcn_mfma_f32_16x16x32_bf16(af[i], bl[j], acc[i][j], 0, 0, 0);
            }
    }

    // epilogue: i-outer keeps the NORM row-partials to 4 live regs
#pragma unroll
    for (int i = 0; i < 4; i++) {
        int mbase = m0 + wrow * 64 + i * 16 + quad * 4;
        float rs[4] = {0.f, 0.f, 0.f, 0.f};
#pragma unroll
        for (int j = 0; j < 4; j++) {
            int n = n0 + wcol * 64 + j * 16 + l15;
            float bv = bias[n];
#pragma unroll
            for (int r = 0; r < 4; r++) {
                int m = mbase + r;
                if (m < M) {
                    float v = fmaxf(acc[i][j][r] + bv, 0.0f);
                    if (NORM) rs[r] += v * v;
                    if (F32OUT) outF[(size_t)m * N + n] = v;
                    else        outB[(size_t)m * N + n] = f2bf(v);
                }
            }
        }
        if (NORM) {
#pragma unroll
            for (int r = 0; r < 4; r++) {
                float s = rs[r];
                s += __shfl_xor(s, 1);
                s += __shfl_xor(s, 2);
                s += __shfl_xor(s, 4);
                s += __shfl_xor(s, 8);
                int m = mbase + r;
                if (l15 == 0 && m < M) atomicAdd(&ssOut[m], s);
            }
        }
    }
}

// ---------- softmax over 512 classes (fp32) ----------
__global__ __launch_bounds__(256) void softmax_k(const float* __restrict__ logits,
                                                 float* __restrict__ probs) {
    int node = blockIdx.x * 4 + (threadIdx.x >> 6);
    int lane = threadIdx.x & 63;
    const float4* zp = (const float4*)(logits + (size_t)node * 512);
    float4 q0 = zp[lane * 2], q1 = zp[lane * 2 + 1];
    float f[8] = {q0.x, q0.y, q0.z, q0.w, q1.x, q1.y, q1.z, q1.w};
    float m = f[0];
#pragma unroll
    for (int i = 1; i < 8; i++) m = fmaxf(m, f[i]);
#pragma unroll
    for (int off = 32; off > 0; off >>= 1) m = fmaxf(m, __shfl_xor(m, off));
    float e[8], s = 0.f;
#pragma unroll
    for (int i = 0; i < 8; i++) { e[i] = __expf(f[i] - m); s += e[i]; }
#pragma unroll
    for (int off = 32; off > 0; off >>= 1) s += __shfl_xor(s, off);
    float inv = 1.0f / s;
    float4* pp = (float4*)(probs + (size_t)node * 512);
    pp[lane * 2]     = make_float4(e[0] * inv, e[1] * inv, e[2] * inv, e[3] * inv);
    pp[lane * 2 + 1] = make_float4(e[4] * inv, e[5] * inv, e[6] * inv, e[7] * inv);
}

// ---------- host launch ----------
extern "C" void kernel_launch(void* const* d_in, const int* in_sizes, int n_in,
                              void* d_out, int out_size, void* d_ws, size_t ws_size,
                              hipStream_t stream) {
    (void)in_sizes; (void)n_in; (void)out_size; (void)ws_size;
    const float* x = (const float*)d_in[0];
    const int* ei = (const int*)d_in[1];
    const float* W1 = (const float*)d_in[2];
    const float* b1 = (const float*)d_in[3];
    const float* e1 = (const float*)d_in[4];
    const float* W2 = (const float*)d_in[5];
    const float* b2 = (const float*)d_in[6];
    const float* e2 = (const float*)d_in[7];
    const float* W3 = (const float*)d_in[8];
    const float* b3 = (const float*)d_in[9];
    const float* e3 = (const float*)d_in[10];
    float* out = (float*)d_out;
    float* out_logits = out;
    float* out_probs = out + (size_t)N_NODES * 512;

    // workspace layout (~215 MB)
    char* ws = (char*)d_ws;
    int* rowptr = (int*)ws;                          // 50048 ints
    int* cursor = rowptr + 50048;                    // 50048 ints
    int* csr = cursor + 50048;                       // 800000 ints
    int* bsum = csr + N_EDGES;                       // 256 ints
    int* bpre = bsum + 256;                          // 256 ints
    float* ss = (float*)(bpre + 256);                // 2*50048 floats
    float* ss1 = ss;
    float* ss2 = ss + 50048;
    unsigned short* Wsp = (unsigned short*)(ss + 2 * 50048);
    unsigned short* f0 = Wsp + 3 * 524288;           // x bf16          (51.2 MB)
    unsigned short* fA = f0 + (size_t)N_NODES * 512; // agg out         (51.2 MB)
    unsigned short* f1 = fA + (size_t)N_NODES * 512; // gemm out        (51.2 MB)
    unsigned short* f2 = f1 + (size_t)N_NODES * 512; // scaled feature  (51.2 MB)

    // CSR build + ss zero
    zero_k<<<196, 256, 0, stream>>>(cursor, N_NODES);
    zero_k<<<392, 256, 0, stream>>>((int*)ss, 2 * 50048);
    count_k<<<(N_EDGES + 255) / 256, 256, 0, stream>>>(ei, cursor);
    blocksum_k<<<NB, 256, 0, stream>>>(cursor, bsum);
    bscan_k<<<1, 256, 0, stream>>>(bsum, bpre, rowptr);
    scatter_k<<<NB, 256, 0, stream>>>(cursor, bpre, rowptr);
    fill_k<<<(N_EDGES + 255) / 256, 256, 0, stream>>>(ei, cursor, csr);

    // weight prep (hi/lo bf16, transposed to [n][k])
    wprep_k<<<64, 256, 0, stream>>>(W1, Wsp,           Wsp + 262144);
    wprep_k<<<64, 256, 0, stream>>>(W2, Wsp + 524288,  Wsp + 786432);
    wprep_k<<<64, 256, 0, stream>>>(W3, Wsp + 1048576, Wsp + 1310720);

    // x -> bf16
    xconv_k<<<25000, 256, 0, stream>>>((const float4*)x, (uint2*)f0);

    const int GG = 4 * ((N_NODES + 127) / 128);  // 1564 blocks, 1D

    // layer 1
    agg_k<<<12500, 256, 0, stream>>>((const uint4*)f0, rowptr, csr, e1, (uint4*)fA);
    gemm_k<false, false, true><<<GG, 256, 0, stream>>>(fA, Wsp, Wsp + 262144, b1, f1, nullptr, ss1, N_NODES);
    scale_k<<<12500, 256, 0, stream>>>((const uint4*)f1, ss1, (uint4*)f2);
    // layer 2
    agg_k<<<12500, 256, 0, stream>>>((const uint4*)f2, rowptr, csr, e2, (uint4*)fA);
    gemm_k<false, false, true><<<GG, 256, 0, stream>>>(fA, Wsp + 524288, Wsp + 786432, b2, f1, nullptr, ss2, N_NODES);
    scale_k<<<12500, 256, 0, stream>>>((const uint4*)f1, ss2, (uint4*)f2);
    // layer 3 (split-precision W3, fp32 logits straight to d_out)
    agg_k<<<12500, 256, 0, stream>>>((const uint4*)f2, rowptr, csr, e3, (uint4*)fA);
    gemm_k<true, true, false><<<GG, 256, 0, stream>>>(fA, Wsp + 1048576, Wsp + 1310720, b3, nullptr, out_logits, nullptr, N_NODES);
    // softmax -> probs
    softmax_k<<<N_NODES / 4, 256, 0, stream>>>(out_logits, out_probs);
}

// Round 4
// 989.523 us; speedup vs baseline: 1.2379x; 1.0143x over previous
//
#include <hip/hip_runtime.h>
#include <stdint.h>

#define N_NODES 50000
#define N_EDGES 800000

typedef unsigned int uint32;

// ---------- bf16 helpers ----------
__device__ inline float bflo(uint32 u) { return __builtin_bit_cast(float, u << 16); }
__device__ inline float bfhi(uint32 u) { return __builtin_bit_cast(float, u & 0xffff0000u); }
__device__ inline float bf2f(unsigned short h) { return __builtin_bit_cast(float, (uint32)h << 16); }
__device__ inline unsigned short f2bf(float f) {
    uint32 u = __builtin_bit_cast(uint32, f);
    u += 0x7fffu + ((u >> 16) & 1u);  // RNE
    return (unsigned short)(u >> 16);
}
__device__ inline uint32 pack2(float lo, float hi) {
    return (uint32)f2bf(lo) | ((uint32)f2bf(hi) << 16);
}

// ---------- CSR build ----------
__global__ __launch_bounds__(256) void zero_k(int* p, int n) {
    int i = blockIdx.x * 256 + threadIdx.x;
    if (i < n) p[i] = 0;
}

__global__ __launch_bounds__(256) void count_k(const int* __restrict__ ei, int* __restrict__ cnt) {
    int e = blockIdx.x * 256 + threadIdx.x;
    if (e < N_EDGES) atomicAdd(&cnt[ei[N_EDGES + e]], 1);
}

#define NB 196  // 196*256 = 50176 >= 50000

__global__ __launch_bounds__(256) void blocksum_k(const int* __restrict__ cnt, int* __restrict__ bsum) {
    int i = blockIdx.x * 256 + threadIdx.x;
    int v = (i < N_NODES) ? cnt[i] : 0;
#pragma unroll
    for (int off = 32; off > 0; off >>= 1) v += __shfl_down(v, off);
    __shared__ int sh[4];
    int w = threadIdx.x >> 6, lane = threadIdx.x & 63;
    if (lane == 0) sh[w] = v;
    __syncthreads();
    if (threadIdx.x == 0) bsum[blockIdx.x] = sh[0] + sh[1] + sh[2] + sh[3];
}

__global__ __launch_bounds__(256) void bscan_k(const int* __restrict__ bsum, int* __restrict__ bpre,
                                               int* __restrict__ rowptr) {
    __shared__ int sh[256];
    int t = threadIdx.x;
    int v = (t < NB) ? bsum[t] : 0;
    sh[t] = v;
    __syncthreads();
    for (int d = 1; d < 256; d <<= 1) {
        int u = (t >= d) ? sh[t - d] : 0;
        __syncthreads();
        sh[t] += u;
        __syncthreads();
    }
    if (t < NB) bpre[t] = sh[t] - v;          // exclusive block prefix
    if (t == NB - 1) rowptr[N_NODES] = sh[t]; // total = N_EDGES
}

__global__ __launch_bounds__(256) void scatter_k(int* __restrict__ cnt, const int* __restrict__ bpre,
                                                 int* __restrict__ rowptr) {
    int b = blockIdx.x, t = threadIdx.x, i = b * 256 + t;
    int w = t >> 6, lane = t & 63;
    int myv = (i < N_NODES) ? cnt[i] : 0;
    int v = myv;
#pragma unroll
    for (int d = 1; d < 64; d <<= 1) {
        int u = __shfl_up(v, d);
        if (lane >= d) v += u;
    }
    __shared__ int wt[4];
    if (lane == 63) wt[w] = v;
    __syncthreads();
    int off = bpre[b];
    for (int k = 0; k < w; k++) off += wt[k];
    int excl = v - myv + off;
    if (i < N_NODES) {
        rowptr[i] = excl;
        cnt[i] = excl;  // becomes cursor
    }
}

__global__ __launch_bounds__(256) void fill_k(const int* __restrict__ ei, int* __restrict__ cursor,
                                              int* __restrict__ csr) {
    int e = blockIdx.x * 256 + threadIdx.x;
    if (e < N_EDGES) {
        int d = ei[N_EDGES + e];
        int p = atomicAdd(&cursor[d], 1);
        csr[p] = ei[e];  // src
    }
}

// ---------- weight prep: W fp32 [k][n] -> Whi/Wlo bf16 [n][k], LDS-tiled transpose ----------
__global__ __launch_bounds__(256) void wprep_k(const float* __restrict__ W,
                                               unsigned short* __restrict__ Whi,
                                               unsigned short* __restrict__ Wlo) {
    __shared__ float sh[64][65];  // +1 pad
    int bk = (blockIdx.x & 7) * 64;
    int bn = (blockIdx.x >> 3) * 64;
    int t = threadIdx.x;
    int lr = t >> 4;         // 0..15
    int lc4 = (t & 15) * 4;  // 0,4,..,60
#pragma unroll
    for (int i = 0; i < 4; i++) {
        int k = lr + i * 16;
        float4 v = *(const float4*)&W[(size_t)(bk + k) * 512 + bn + lc4];
        sh[k][lc4] = v.x; sh[k][lc4 + 1] = v.y; sh[k][lc4 + 2] = v.z; sh[k][lc4 + 3] = v.w;
    }
    __syncthreads();
#pragma unroll
    for (int i = 0; i < 4; i++) {
        int n = lr + i * 16;
        float w0 = sh[lc4][n], w1 = sh[lc4 + 1][n], w2 = sh[lc4 + 2][n], w3 = sh[lc4 + 3][n];
        ushort4 h, l;
        h.x = f2bf(w0); l.x = f2bf(w0 - bf2f(h.x));
        h.y = f2bf(w1); l.y = f2bf(w1 - bf2f(h.y));
        h.z = f2bf(w2); l.z = f2bf(w2 - bf2f(h.z));
        h.w = f2bf(w3); l.w = f2bf(w3 - bf2f(h.w));
        *(ushort4*)&Whi[(size_t)(bn + n) * 512 + bk + lc4] = h;
        *(ushort4*)&Wlo[(size_t)(bn + n) * 512 + bk + lc4] = l;
    }
}

// ---------- x fp32 -> bf16 packed (float4 -> uint2) ----------
__global__ __launch_bounds__(256) void xconv_k(const float4* __restrict__ x, uint2* __restrict__ xb) {
    int i = blockIdx.x * 256 + threadIdx.x;  // 6.4M
    float4 v = x[i];
    uint2 o;
    o.x = pack2(v.x, v.y);
    o.y = pack2(v.z, v.w);
    xb[i] = o;
}

// ---------- ss -> inverse norm ----------
__global__ __launch_bounds__(256) void invn_k(const float* __restrict__ ss, float* __restrict__ invn) {
    int i = blockIdx.x * 256 + threadIdx.x;
    if (i < N_NODES) invn[i] = 1.0f / fmaxf(sqrtf(ss[i]), 1e-12f);
}

// ---------- aggregation: wave-per-node, unroll-8, per-edge invn scaling fused ----------
#define ACCW(Q, W)                                                            \
    a0 = fmaf(W, bflo(Q.x), a0); a1 = fmaf(W, bfhi(Q.x), a1);                 \
    a2 = fmaf(W, bflo(Q.y), a2); a3 = fmaf(W, bfhi(Q.y), a3);                 \
    a4 = fmaf(W, bflo(Q.z), a4); a5 = fmaf(W, bfhi(Q.z), a5);                 \
    a6 = fmaf(W, bflo(Q.w), a6); a7 = fmaf(W, bfhi(Q.w), a7);

template <bool SCALED>
__global__ __launch_bounds__(256) void agg_k(const uint4* __restrict__ xin,
                                             const int* __restrict__ rowptr,
                                             const int* __restrict__ csr,
                                             const float* __restrict__ eps,
                                             const float* __restrict__ invn,
                                             uint4* __restrict__ hout) {
    int node = blockIdx.x * 4 + (threadIdx.x >> 6);
    int lane = threadIdx.x & 63;
    int beg = rowptr[node], end = rowptr[node + 1];
    float a0 = 0.f, a1 = 0.f, a2 = 0.f, a3 = 0.f, a4 = 0.f, a5 = 0.f, a6 = 0.f, a7 = 0.f;
    int e = beg;
    for (; e + 8 <= end; e += 8) {
        int s0 = csr[e],     s1 = csr[e + 1], s2 = csr[e + 2], s3 = csr[e + 3];
        int s4 = csr[e + 4], s5 = csr[e + 5], s6 = csr[e + 6], s7 = csr[e + 7];
        uint4 q0 = xin[(size_t)s0 * 64 + lane];
        uint4 q1 = xin[(size_t)s1 * 64 + lane];
        uint4 q2 = xin[(size_t)s2 * 64 + lane];
        uint4 q3 = xin[(size_t)s3 * 64 + lane];
        uint4 q4 = xin[(size_t)s4 * 64 + lane];
        uint4 q5 = xin[(size_t)s5 * 64 + lane];
        uint4 q6 = xin[(size_t)s6 * 64 + lane];
        uint4 q7 = xin[(size_t)s7 * 64 + lane];
        float w0 = SCALED ? invn[s0] : 1.0f;
        float w1 = SCALED ? invn[s1] : 1.0f;
        float w2 = SCALED ? invn[s2] : 1.0f;
        float w3 = SCALED ? invn[s3] : 1.0f;
        float w4 = SCALED ? invn[s4] : 1.0f;
        float w5 = SCALED ? invn[s5] : 1.0f;
        float w6 = SCALED ? invn[s6] : 1.0f;
        float w7 = SCALED ? invn[s7] : 1.0f;
        ACCW(q0, w0) ACCW(q1, w1) ACCW(q2, w2) ACCW(q3, w3)
        ACCW(q4, w4) ACCW(q5, w5) ACCW(q6, w6) ACCW(q7, w7)
    }
    for (; e < end; ++e) {
        int s0 = csr[e];
        uint4 q0 = xin[(size_t)s0 * 64 + lane];
        float w0 = SCALED ? invn[s0] : 1.0f;
        ACCW(q0, w0)
    }
    uint4 qs = xin[(size_t)node * 64 + lane];
    float wsf = (1.0f + eps[0]) * (SCALED ? invn[node] : 1.0f);
    ACCW(qs, wsf)
    uint4 o;
    o.x = pack2(a0, a1);
    o.y = pack2(a2, a3);
    o.z = pack2(a4, a5);
    o.w = pack2(a6, a7);
    hout[(size_t)node * 64 + lane] = o;
}

// ---------- GEMM: relu(A[M,512](bf16) @ W[512,512] + b(fp32)), fused row-sum-of-squares ----------
// 2-phase prefetch: double-buffered LDS, stage(t+1) issued BEFORE compute(t), single barrier per
// K-step whose implicit vmcnt(0)+lgkmcnt(0) drain gives the needed buffer-ready / reads-done sync.
// 1D grid with bijective XCD-chunk swizzle (n-fastest) so same-m blocks share A-tile in one L2.
typedef __bf16 bf16x8 __attribute__((ext_vector_type(8)));
typedef float f32x4 __attribute__((ext_vector_type(4)));

__device__ inline void async16(const void* g, void* l) {
    __builtin_amdgcn_global_load_lds((const __attribute__((address_space(1))) void*)g,
                                     (__attribute__((address_space(3))) void*)l, 16, 0, 0);
}

template <bool SPLIT, bool F32OUT, bool NORM>
__global__ __launch_bounds__(256) void gemm_k(const unsigned short* __restrict__ A,
                                              const unsigned short* __restrict__ Whi,
                                              const unsigned short* __restrict__ Wlo,
                                              const float* __restrict__ bias,
                                              unsigned short* __restrict__ outB,
                                              float* __restrict__ outF,
                                              float* __restrict__ ssOut, int M) {
    constexpr int K = 512, N = 512, BK = 32, TM = 128, NK = K / BK;  // 16 K-steps
    constexpr int BUF = TM * BK;  // 4096 elems / 8 KB per buffer
    __shared__ unsigned short lds_a[2 * BUF];
    __shared__ unsigned short lds_bh[2 * BUF];
    __shared__ unsigned short lds_bl[SPLIT ? 2 * BUF : 16];
    const int t = threadIdx.x;
    const int w = t >> 6, lane = t & 63;
    const int wrow = w >> 1, wcol = w & 1;

    // bijective XCD swizzle: xcd = bid%8 gets a contiguous chunk of wg-space
    const int nwg = gridDim.x;
    const int qd = nwg >> 3, rd = nwg & 7;
    const int xcd = blockIdx.x & 7, jj = blockIdx.x >> 3;
    const int wg = (xcd < rd ? xcd * (qd + 1) : rd * (qd + 1) + (xcd - rd) * qd) + jj;
    const int m0 = (wg >> 2) * TM;  // n-fastest: same-m blocks adjacent on same XCD
    const int n0 = (wg & 3) * TM;

    int r0 = w * 16 + (lane >> 2), cc = (lane & 3) * 8;
    int r1 = 64 + r0;
    int am0 = m0 + r0; am0 = am0 < M ? am0 : M - 1;
    int am1 = m0 + r1; am1 = am1 < M ? am1 : M - 1;
    const unsigned short* ag0 = A + (size_t)am0 * K + cc;
    const unsigned short* ag1 = A + (size_t)am1 * K + cc;
    const unsigned short* bh0 = Whi + (size_t)(n0 + r0) * K + cc;
    const unsigned short* bh1 = Whi + (size_t)(n0 + r1) * K + cc;
    const unsigned short* bl0 = Wlo + (size_t)(n0 + r0) * K + cc;
    const unsigned short* bl1 = Wlo + (size_t)(n0 + r1) * K + cc;
    const int wo = w * 512;  // wave's staging offset within a buffer half

    f32x4 acc[4][4] = {};
    const int quad = lane >> 4, l15 = lane & 15;
    const int arow = wrow * 64 + l15;
    const int brow = wcol * 64 + l15;

    auto stage = [&](int k0, int buf) {
        unsigned short* da = lds_a + buf * BUF + wo;
        unsigned short* dh = lds_bh + buf * BUF + wo;
        async16(ag0 + k0, da);
        async16(ag1 + k0, da + 2048);
        async16(bh0 + k0, dh);
        async16(bh1 + k0, dh + 2048);
        if (SPLIT) {
            unsigned short* dl = lds_bl + buf * BUF + wo;
            async16(bl0 + k0, dl);
            async16(bl1 + k0, dl + 2048);
        }
    };

    auto compute = [&](int buf) {
        const unsigned short* ba = lds_a + buf * BUF;
        const unsigned short* bb = lds_bh + buf * BUF;
        bf16x8 af[4], bhf[4], blf[4];
#pragma unroll
        for (int i = 0; i < 4; i++)
            af[i] = *(const bf16x8*)&ba[(arow + i * 16) * BK + quad * 8];
#pragma unroll
        for (int j = 0; j < 4; j++)
            bhf[j] = *(const bf16x8*)&bb[(brow + j * 16) * BK + quad * 8];
        if (SPLIT) {
            const unsigned short* bl = lds_bl + buf * BUF;
#pragma unroll
            for (int j = 0; j < 4; j++)
                blf[j] = *(const bf16x8*)&bl[(brow + j * 16) * BK + quad * 8];
        }
#pragma unroll
        for (int i = 0; i < 4; i++)
#pragma unroll
            for (int j = 0; j < 4; j++) {
                acc[i][j] = __builtin_amdgcn_mfma_f32_16x16x32_bf16(af[i], bhf[j], acc[i][j], 0, 0, 0);
                if (SPLIT)
                    acc[i][j] = __builtin_amdgcn_mfma_f32_16x16x32_bf16(af[i], blf[j], acc[i][j], 0, 0, 0);
            }
    };

    // prologue
    stage(0, 0);
    __syncthreads();  // drain: buf0 ready
    int cur = 0;
    for (int ks = 0; ks < NK - 1; ++ks) {
        stage((ks + 1) * BK, cur ^ 1);  // loads fly under compute
        compute(cur);
        __syncthreads();  // implicit vmcnt(0)+lgkmcnt(0): buf[cur^1] ready, buf[cur] reads done
        cur ^= 1;
    }
    compute(cur);  // last tile

    // epilogue: i-outer keeps the NORM row-partials to 4 live regs
#pragma unroll
    for (int i = 0; i < 4; i++) {
        int mbase = m0 + wrow * 64 + i * 16 + quad * 4;
        float rs[4] = {0.f, 0.f, 0.f, 0.f};
#pragma unroll
        for (int j = 0; j < 4; j++) {
            int n = n0 + wcol * 64 + j * 16 + l15;
            float bv = bias[n];
#pragma unroll
            for (int r = 0; r < 4; r++) {
                int m = mbase + r;
                if (m < M) {
                    float v = fmaxf(acc[i][j][r] + bv, 0.0f);
                    if (NORM) rs[r] += v * v;
                    if (F32OUT) outF[(size_t)m * N + n] = v;
                    else        outB[(size_t)m * N + n] = f2bf(v);
                }
            }
        }
        if (NORM) {
#pragma unroll
            for (int r = 0; r < 4; r++) {
                float s = rs[r];
                s += __shfl_xor(s, 1);
                s += __shfl_xor(s, 2);
                s += __shfl_xor(s, 4);
                s += __shfl_xor(s, 8);
                int m = mbase + r;
                if (l15 == 0 && m < M) atomicAdd(&ssOut[m], s);
            }
        }
    }
}

// ---------- softmax over 512 classes (fp32) ----------
__global__ __launch_bounds__(256) void softmax_k(const float* __restrict__ logits,
                                                 float* __restrict__ probs) {
    int node = blockIdx.x * 4 + (threadIdx.x >> 6);
    int lane = threadIdx.x & 63;
    const float4* zp = (const float4*)(logits + (size_t)node * 512);
    float4 q0 = zp[lane * 2], q1 = zp[lane * 2 + 1];
    float f[8] = {q0.x, q0.y, q0.z, q0.w, q1.x, q1.y, q1.z, q1.w};
    float m = f[0];
#pragma unroll
    for (int i = 1; i < 8; i++) m = fmaxf(m, f[i]);
#pragma unroll
    for (int off = 32; off > 0; off >>= 1) m = fmaxf(m, __shfl_xor(m, off));
    float e[8], s = 0.f;
#pragma unroll
    for (int i = 0; i < 8; i++) { e[i] = __expf(f[i] - m); s += e[i]; }
#pragma unroll
    for (int off = 32; off > 0; off >>= 1) s += __shfl_xor(s, off);
    float inv = 1.0f / s;
    float4* pp = (float4*)(probs + (size_t)node * 512);
    pp[lane * 2]     = make_float4(e[0] * inv, e[1] * inv, e[2] * inv, e[3] * inv);
    pp[lane * 2 + 1] = make_float4(e[4] * inv, e[5] * inv, e[6] * inv, e[7] * inv);
}

// ---------- host launch ----------
extern "C" void kernel_launch(void* const* d_in, const int* in_sizes, int n_in,
                              void* d_out, int out_size, void* d_ws, size_t ws_size,
                              hipStream_t stream) {
    (void)in_sizes; (void)n_in; (void)out_size; (void)ws_size;
    const float* x = (const float*)d_in[0];
    const int* ei = (const int*)d_in[1];
    const float* W1 = (const float*)d_in[2];
    const float* b1 = (const float*)d_in[3];
    const float* e1 = (const float*)d_in[4];
    const float* W2 = (const float*)d_in[5];
    const float* b2 = (const float*)d_in[6];
    const float* e2 = (const float*)d_in[7];
    const float* W3 = (const float*)d_in[8];
    const float* b3 = (const float*)d_in[9];
    const float* e3 = (const float*)d_in[10];
    float* out = (float*)d_out;
    float* out_logits = out;
    float* out_probs = out + (size_t)N_NODES * 512;

    // workspace layout (~165 MB)
    char* ws = (char*)d_ws;
    int* rowptr = (int*)ws;                          // 50048 ints
    int* cursor = rowptr + 50048;                    // 50048 ints
    int* csr = cursor + 50048;                       // 800000 ints
    int* bsum = csr + N_EDGES;                       // 256 ints
    int* bpre = bsum + 256;                          // 256 ints
    float* invn = (float*)(bpre + 256);              // 50048 floats
    float* ss = invn + 50048;                        // 2*50048 floats
    float* ss1 = ss;
    float* ss2 = ss + 50048;
    unsigned short* Wsp = (unsigned short*)(ss + 2 * 50048);
    unsigned short* f0 = Wsp + 3 * 524288;           // x bf16   (51.2 MB)
    unsigned short* fA = f0 + (size_t)N_NODES * 512; // agg out  (51.2 MB)
    unsigned short* f1 = fA + (size_t)N_NODES * 512; // gemm out (51.2 MB)

    // CSR build + ss zero
    zero_k<<<196, 256, 0, stream>>>(cursor, N_NODES);
    zero_k<<<392, 256, 0, stream>>>((int*)ss, 2 * 50048);
    count_k<<<(N_EDGES + 255) / 256, 256, 0, stream>>>(ei, cursor);
    blocksum_k<<<NB, 256, 0, stream>>>(cursor, bsum);
    bscan_k<<<1, 256, 0, stream>>>(bsum, bpre, rowptr);
    scatter_k<<<NB, 256, 0, stream>>>(cursor, bpre, rowptr);
    fill_k<<<(N_EDGES + 255) / 256, 256, 0, stream>>>(ei, cursor, csr);

    // weight prep (hi/lo bf16, transposed to [n][k])
    wprep_k<<<64, 256, 0, stream>>>(W1, Wsp,           Wsp + 262144);
    wprep_k<<<64, 256, 0, stream>>>(W2, Wsp + 524288,  Wsp + 786432);
    wprep_k<<<64, 256, 0, stream>>>(W3, Wsp + 1048576, Wsp + 1310720);

    // x -> bf16
    xconv_k<<<25000, 256, 0, stream>>>((const float4*)x, (uint2*)f0);

    const int GG = 4 * ((N_NODES + 127) / 128);  // 1564 blocks, 1D

    // layer 1
    agg_k<false><<<12500, 256, 0, stream>>>((const uint4*)f0, rowptr, csr, e1, nullptr, (uint4*)fA);
    gemm_k<false, false, true><<<GG, 256, 0, stream>>>(fA, Wsp, Wsp + 262144, b1, f1, nullptr, ss1, N_NODES);
    // layer 2 (invn from fused ss; normalize fused into agg per-edge)
    invn_k<<<196, 256, 0, stream>>>(ss1, invn);
    agg_k<true><<<12500, 256, 0, stream>>>((const uint4*)f1, rowptr, csr, e2, invn, (uint4*)fA);
    gemm_k<false, false, true><<<GG, 256, 0, stream>>>(fA, Wsp + 524288, Wsp + 786432, b2, f1, nullptr, ss2, N_NODES);
    // layer 3 (split-precision W3, fp32 logits straight to d_out)
    invn_k<<<196, 256, 0, stream>>>(ss2, invn);
    agg_k<true><<<12500, 256, 0, stream>>>((const uint4*)f1, rowptr, csr, e3, invn, (uint4*)fA);
    gemm_k<true, true, false><<<GG, 256, 0, stream>>>(fA, Wsp + 1048576, Wsp + 1310720, b3, nullptr, out_logits, nullptr, N_NODES);
    // softmax -> probs
    softmax_k<<<N_NODES / 4, 256, 0, stream>>>(out_logits, out_probs);
}

// Round 5
// 938.944 us; speedup vs baseline: 1.3046x; 1.0539x over previous
//
#include <hip/hip_runtime.h>
#include <stdint.h>

#define N_NODES 50000
#define N_EDGES 800000

typedef unsigned int uint32;

// ---------- bf16 helpers ----------
__device__ inline float bflo(uint32 u) { return __builtin_bit_cast(float, u << 16); }
__device__ inline float bfhi(uint32 u) { return __builtin_bit_cast(float, u & 0xffff0000u); }
__device__ inline float bf2f(unsigned short h) { return __builtin_bit_cast(float, (uint32)h << 16); }
__device__ inline unsigned short f2bf(float f) {
    uint32 u = __builtin_bit_cast(uint32, f);
    u += 0x7fffu + ((u >> 16) & 1u);  // RNE
    return (unsigned short)(u >> 16);
}
__device__ inline uint32 pack2(float lo, float hi) {
    return (uint32)f2bf(lo) | ((uint32)f2bf(hi) << 16);
}

// ---------- CSR build ----------
__global__ __launch_bounds__(256) void zero_k(int* p, int n) {
    int i = blockIdx.x * 256 + threadIdx.x;
    if (i < n) p[i] = 0;
}

__global__ __launch_bounds__(256) void count_k(const int* __restrict__ ei, int* __restrict__ cnt) {
    int e = blockIdx.x * 256 + threadIdx.x;
    if (e < N_EDGES) atomicAdd(&cnt[ei[N_EDGES + e]], 1);
}

#define NB 196  // 196*256 = 50176 >= 50000

__global__ __launch_bounds__(256) void blocksum_k(const int* __restrict__ cnt, int* __restrict__ bsum) {
    int i = blockIdx.x * 256 + threadIdx.x;
    int v = (i < N_NODES) ? cnt[i] : 0;
#pragma unroll
    for (int off = 32; off > 0; off >>= 1) v += __shfl_down(v, off);
    __shared__ int sh[4];
    int w = threadIdx.x >> 6, lane = threadIdx.x & 63;
    if (lane == 0) sh[w] = v;
    __syncthreads();
    if (threadIdx.x == 0) bsum[blockIdx.x] = sh[0] + sh[1] + sh[2] + sh[3];
}

__global__ __launch_bounds__(256) void bscan_k(const int* __restrict__ bsum, int* __restrict__ bpre,
                                               int* __restrict__ rowptr) {
    __shared__ int sh[256];
    int t = threadIdx.x;
    int v = (t < NB) ? bsum[t] : 0;
    sh[t] = v;
    __syncthreads();
    for (int d = 1; d < 256; d <<= 1) {
        int u = (t >= d) ? sh[t - d] : 0;
        __syncthreads();
        sh[t] += u;
        __syncthreads();
    }
    if (t < NB) bpre[t] = sh[t] - v;          // exclusive block prefix
    if (t == NB - 1) rowptr[N_NODES] = sh[t]; // total = N_EDGES
}

__global__ __launch_bounds__(256) void scatter_k(int* __restrict__ cnt, const int* __restrict__ bpre,
                                                 int* __restrict__ rowptr) {
    int b = blockIdx.x, t = threadIdx.x, i = b * 256 + t;
    int w = t >> 6, lane = t & 63;
    int myv = (i < N_NODES) ? cnt[i] : 0;
    int v = myv;
#pragma unroll
    for (int d = 1; d < 64; d <<= 1) {
        int u = __shfl_up(v, d);
        if (lane >= d) v += u;
    }
    __shared__ int wt[4];
    if (lane == 63) wt[w] = v;
    __syncthreads();
    int off = bpre[b];
    for (int k = 0; k < w; k++) off += wt[k];
    int excl = v - myv + off;
    if (i < N_NODES) {
        rowptr[i] = excl;
        cnt[i] = excl;  // becomes cursor
    }
}

__global__ __launch_bounds__(256) void fill_k(const int* __restrict__ ei, int* __restrict__ cursor,
                                              int* __restrict__ csr) {
    int e = blockIdx.x * 256 + threadIdx.x;
    if (e < N_EDGES) {
        int d = ei[N_EDGES + e];
        int p = atomicAdd(&cursor[d], 1);
        csr[p] = ei[e];  // src
    }
}

// ---------- weight prep: W fp32 [k][n] -> Whi/Wlo bf16 [n][k], LDS-tiled transpose ----------
__global__ __launch_bounds__(256) void wprep_k(const float* __restrict__ W,
                                               unsigned short* __restrict__ Whi,
                                               unsigned short* __restrict__ Wlo) {
    __shared__ float sh[64][65];  // +1 pad
    int bk = (blockIdx.x & 7) * 64;
    int bn = (blockIdx.x >> 3) * 64;
    int t = threadIdx.x;
    int lr = t >> 4;         // 0..15
    int lc4 = (t & 15) * 4;  // 0,4,..,60
#pragma unroll
    for (int i = 0; i < 4; i++) {
        int k = lr + i * 16;
        float4 v = *(const float4*)&W[(size_t)(bk + k) * 512 + bn + lc4];
        sh[k][lc4] = v.x; sh[k][lc4 + 1] = v.y; sh[k][lc4 + 2] = v.z; sh[k][lc4 + 3] = v.w;
    }
    __syncthreads();
#pragma unroll
    for (int i = 0; i < 4; i++) {
        int n = lr + i * 16;
        float w0 = sh[lc4][n], w1 = sh[lc4 + 1][n], w2 = sh[lc4 + 2][n], w3 = sh[lc4 + 3][n];
        ushort4 h, l;
        h.x = f2bf(w0); l.x = f2bf(w0 - bf2f(h.x));
        h.y = f2bf(w1); l.y = f2bf(w1 - bf2f(h.y));
        h.z = f2bf(w2); l.z = f2bf(w2 - bf2f(h.z));
        h.w = f2bf(w3); l.w = f2bf(w3 - bf2f(h.w));
        *(ushort4*)&Whi[(size_t)(bn + n) * 512 + bk + lc4] = h;
        *(ushort4*)&Wlo[(size_t)(bn + n) * 512 + bk + lc4] = l;
    }
}

// ---------- x fp32 -> bf16 packed (float4 -> uint2) ----------
__global__ __launch_bounds__(256) void xconv_k(const float4* __restrict__ x, uint2* __restrict__ xb) {
    int i = blockIdx.x * 256 + threadIdx.x;  // 6.4M
    float4 v = x[i];
    uint2 o;
    o.x = pack2(v.x, v.y);
    o.y = pack2(v.z, v.w);
    xb[i] = o;
}

// ---------- aggregation over PRE-TRANSFORMED features (GEMM-first order) ----------
// Each wave owns one node and holds its full 512-wide row: bias/relu/l2norm are wave-local.
// NORM=true  (layers 1,2): out = relu(sum + bias) * 1/max(||relu(sum+bias)||,1e-12)
// NORM=false (layer 3 pre-GEMM gather): out = raw sum (bias applied later in gemm3)
#define ACC8(Q)                                                          \
    a0 += bflo(Q.x); a1 += bfhi(Q.x); a2 += bflo(Q.y); a3 += bfhi(Q.y);  \
    a4 += bflo(Q.z); a5 += bfhi(Q.z); a6 += bflo(Q.w); a7 += bfhi(Q.w);

template <bool NORM>
__global__ __launch_bounds__(256) void agg_k(const uint4* __restrict__ xin,
                                             const int* __restrict__ rowptr,
                                             const int* __restrict__ csr,
                                             const float* __restrict__ eps,
                                             const float* __restrict__ bias,
                                             uint4* __restrict__ hout) {
    int node = blockIdx.x * 4 + (threadIdx.x >> 6);
    int lane = threadIdx.x & 63;
    int beg = rowptr[node], end = rowptr[node + 1];
    float a0 = 0.f, a1 = 0.f, a2 = 0.f, a3 = 0.f, a4 = 0.f, a5 = 0.f, a6 = 0.f, a7 = 0.f;
    int e = beg;
    for (; e + 8 <= end; e += 8) {
        int s0 = csr[e],     s1 = csr[e + 1], s2 = csr[e + 2], s3 = csr[e + 3];
        int s4 = csr[e + 4], s5 = csr[e + 5], s6 = csr[e + 6], s7 = csr[e + 7];
        uint4 q0 = xin[(size_t)s0 * 64 + lane];
        uint4 q1 = xin[(size_t)s1 * 64 + lane];
        uint4 q2 = xin[(size_t)s2 * 64 + lane];
        uint4 q3 = xin[(size_t)s3 * 64 + lane];
        uint4 q4 = xin[(size_t)s4 * 64 + lane];
        uint4 q5 = xin[(size_t)s5 * 64 + lane];
        uint4 q6 = xin[(size_t)s6 * 64 + lane];
        uint4 q7 = xin[(size_t)s7 * 64 + lane];
        ACC8(q0) ACC8(q1) ACC8(q2) ACC8(q3)
        ACC8(q4) ACC8(q5) ACC8(q6) ACC8(q7)
    }
    for (; e < end; ++e) {
        int s0 = csr[e];
        uint4 q0 = xin[(size_t)s0 * 64 + lane];
        ACC8(q0)
    }
    // self term
    uint4 qs = xin[(size_t)node * 64 + lane];
    float ws = 1.0f + eps[0];
    a0 = fmaf(ws, bflo(qs.x), a0); a1 = fmaf(ws, bfhi(qs.x), a1);
    a2 = fmaf(ws, bflo(qs.y), a2); a3 = fmaf(ws, bfhi(qs.y), a3);
    a4 = fmaf(ws, bflo(qs.z), a4); a5 = fmaf(ws, bfhi(qs.z), a5);
    a6 = fmaf(ws, bflo(qs.w), a6); a7 = fmaf(ws, bfhi(qs.w), a7);

    uint4 o;
    if (NORM) {
        // bias + relu (lane owns columns lane*8 .. lane*8+7)
        float4 b0 = *(const float4*)(bias + lane * 8);
        float4 b1 = *(const float4*)(bias + lane * 8 + 4);
        float h0 = fmaxf(a0 + b0.x, 0.f), h1 = fmaxf(a1 + b0.y, 0.f);
        float h2 = fmaxf(a2 + b0.z, 0.f), h3 = fmaxf(a3 + b0.w, 0.f);
        float h4 = fmaxf(a4 + b1.x, 0.f), h5 = fmaxf(a5 + b1.y, 0.f);
        float h6 = fmaxf(a6 + b1.z, 0.f), h7 = fmaxf(a7 + b1.w, 0.f);
        // wave-local L2 norm over the full 512 row
        float ssl = h0 * h0 + h1 * h1 + h2 * h2 + h3 * h3 + h4 * h4 + h5 * h5 + h6 * h6 + h7 * h7;
#pragma unroll
        for (int off = 32; off > 0; off >>= 1) ssl += __shfl_xor(ssl, off);
        float inv = 1.0f / fmaxf(sqrtf(ssl), 1e-12f);
        o.x = pack2(h0 * inv, h1 * inv);
        o.y = pack2(h2 * inv, h3 * inv);
        o.z = pack2(h4 * inv, h5 * inv);
        o.w = pack2(h6 * inv, h7 * inv);
    } else {
        o.x = pack2(a0, a1);
        o.y = pack2(a2, a3);
        o.z = pack2(a4, a5);
        o.w = pack2(a6, a7);
    }
    hout[(size_t)node * 64 + lane] = o;
}

// ---------- GEMM: A[M,512](bf16) @ W[512,512] ----------
// F32OUT=false (layers 1,2): raw linear map, pack to bf16 (bias/relu live in agg).
// F32OUT=true  (layer 3): split-precision W, + bias, relu, fp32 logits.
// 2-phase prefetch double-buffered LDS; 1D grid, bijective XCD-chunk swizzle (n-fastest).
typedef __bf16 bf16x8 __attribute__((ext_vector_type(8)));
typedef float f32x4 __attribute__((ext_vector_type(4)));

__device__ inline void async16(const void* g, void* l) {
    __builtin_amdgcn_global_load_lds((const __attribute__((address_space(1))) void*)g,
                                     (__attribute__((address_space(3))) void*)l, 16, 0, 0);
}

template <bool SPLIT, bool F32OUT>
__global__ __launch_bounds__(256) void gemm_k(const unsigned short* __restrict__ A,
                                              const unsigned short* __restrict__ Whi,
                                              const unsigned short* __restrict__ Wlo,
                                              const float* __restrict__ bias,
                                              unsigned short* __restrict__ outB,
                                              float* __restrict__ outF, int M) {
    constexpr int K = 512, N = 512, BK = 32, TM = 128, NK = K / BK;  // 16 K-steps
    constexpr int BUF = TM * BK;  // 4096 elems / 8 KB per buffer
    __shared__ unsigned short lds_a[2 * BUF];
    __shared__ unsigned short lds_bh[2 * BUF];
    __shared__ unsigned short lds_bl[SPLIT ? 2 * BUF : 16];
    const int t = threadIdx.x;
    const int w = t >> 6, lane = t & 63;
    const int wrow = w >> 1, wcol = w & 1;

    // bijective XCD swizzle: xcd = bid%8 gets a contiguous chunk of wg-space
    const int nwg = gridDim.x;
    const int qd = nwg >> 3, rd = nwg & 7;
    const int xcd = blockIdx.x & 7, jj = blockIdx.x >> 3;
    const int wg = (xcd < rd ? xcd * (qd + 1) : rd * (qd + 1) + (xcd - rd) * qd) + jj;
    const int m0 = (wg >> 2) * TM;  // n-fastest: same-m blocks adjacent on same XCD
    const int n0 = (wg & 3) * TM;

    int r0 = w * 16 + (lane >> 2), cc = (lane & 3) * 8;
    int r1 = 64 + r0;
    int am0 = m0 + r0; am0 = am0 < M ? am0 : M - 1;
    int am1 = m0 + r1; am1 = am1 < M ? am1 : M - 1;
    const unsigned short* ag0 = A + (size_t)am0 * K + cc;
    const unsigned short* ag1 = A + (size_t)am1 * K + cc;
    const unsigned short* bh0 = Whi + (size_t)(n0 + r0) * K + cc;
    const unsigned short* bh1 = Whi + (size_t)(n0 + r1) * K + cc;
    const unsigned short* bl0 = Wlo + (size_t)(n0 + r0) * K + cc;
    const unsigned short* bl1 = Wlo + (size_t)(n0 + r1) * K + cc;
    const int wo = w * 512;  // wave's staging offset within a buffer half

    f32x4 acc[4][4] = {};
    const int quad = lane >> 4, l15 = lane & 15;
    const int arow = wrow * 64 + l15;
    const int brow = wcol * 64 + l15;

    auto stage = [&](int k0, int buf) {
        unsigned short* da = lds_a + buf * BUF + wo;
        unsigned short* dh = lds_bh + buf * BUF + wo;
        async16(ag0 + k0, da);
        async16(ag1 + k0, da + 2048);
        async16(bh0 + k0, dh);
        async16(bh1 + k0, dh + 2048);
        if (SPLIT) {
            unsigned short* dl = lds_bl + buf * BUF + wo;
            async16(bl0 + k0, dl);
            async16(bl1 + k0, dl + 2048);
        }
    };

    auto compute = [&](int buf) {
        const unsigned short* ba = lds_a + buf * BUF;
        const unsigned short* bb = lds_bh + buf * BUF;
        bf16x8 af[4], bhf[4], blf[4];
#pragma unroll
        for (int i = 0; i < 4; i++)
            af[i] = *(const bf16x8*)&ba[(arow + i * 16) * BK + quad * 8];
#pragma unroll
        for (int j = 0; j < 4; j++)
            bhf[j] = *(const bf16x8*)&bb[(brow + j * 16) * BK + quad * 8];
        if (SPLIT) {
            const unsigned short* bl = lds_bl + buf * BUF;
#pragma unroll
            for (int j = 0; j < 4; j++)
                blf[j] = *(const bf16x8*)&bl[(brow + j * 16) * BK + quad * 8];
        }
#pragma unroll
        for (int i = 0; i < 4; i++)
#pragma unroll
            for (int j = 0; j < 4; j++) {
                acc[i][j] = __builtin_amdgcn_mfma_f32_16x16x32_bf16(af[i], bhf[j], acc[i][j], 0, 0, 0);
                if (SPLIT)
                    acc[i][j] = __builtin_amdgcn_mfma_f32_16x16x32_bf16(af[i], blf[j], acc[i][j], 0, 0, 0);
            }
    };

    // prologue
    stage(0, 0);
    __syncthreads();  // drain: buf0 ready
    int cur = 0;
    for (int ks = 0; ks < NK - 1; ++ks) {
        stage((ks + 1) * BK, cur ^ 1);  // loads fly under compute
        compute(cur);
        __syncthreads();  // implicit vmcnt(0)+lgkmcnt(0): buf[cur^1] ready, buf[cur] reads done
        cur ^= 1;
    }
    compute(cur);  // last tile

    // epilogue
#pragma unroll
    for (int i = 0; i < 4; i++) {
        int mbase = m0 + wrow * 64 + i * 16 + quad * 4;
#pragma unroll
        for (int j = 0; j < 4; j++) {
            int n = n0 + wcol * 64 + j * 16 + l15;
            float bv = F32OUT ? bias[n] : 0.0f;
#pragma unroll
            for (int r = 0; r < 4; r++) {
                int m = mbase + r;
                if (m < M) {
                    if (F32OUT) {
                        outF[(size_t)m * N + n] = fmaxf(acc[i][j][r] + bv, 0.0f);  // logits = relu(.+b)
                    } else {
                        outB[(size_t)m * N + n] = f2bf(acc[i][j][r]);  // raw linear map
                    }
                }
            }
        }
    }
}

// ---------- softmax over 512 classes (fp32) ----------
__global__ __launch_bounds__(256) void softmax_k(const float* __restrict__ logits,
                                                 float* __restrict__ probs) {
    int node = blockIdx.x * 4 + (threadIdx.x >> 6);
    int lane = threadIdx.x & 63;
    const float4* zp = (const float4*)(logits + (size_t)node * 512);
    float4 q0 = zp[lane * 2], q1 = zp[lane * 2 + 1];
    float f[8] = {q0.x, q0.y, q0.z, q0.w, q1.x, q1.y, q1.z, q1.w};
    float m = f[0];
#pragma unroll
    for (int i = 1; i < 8; i++) m = fmaxf(m, f[i]);
#pragma unroll
    for (int off = 32; off > 0; off >>= 1) m = fmaxf(m, __shfl_xor(m, off));
    float e[8], s = 0.f;
#pragma unroll
    for (int i = 0; i < 8; i++) { e[i] = __expf(f[i] - m); s += e[i]; }
#pragma unroll
    for (int off = 32; off > 0; off >>= 1) s += __shfl_xor(s, off);
    float inv = 1.0f / s;
    float4* pp = (float4*)(probs + (size_t)node * 512);
    pp[lane * 2]     = make_float4(e[0] * inv, e[1] * inv, e[2] * inv, e[3] * inv);
    pp[lane * 2 + 1] = make_float4(e[4] * inv, e[5] * inv, e[6] * inv, e[7] * inv);
}

// ---------- host launch ----------
extern "C" void kernel_launch(void* const* d_in, const int* in_sizes, int n_in,
                              void* d_out, int out_size, void* d_ws, size_t ws_size,
                              hipStream_t stream) {
    (void)in_sizes; (void)n_in; (void)out_size; (void)ws_size;
    const float* x = (const float*)d_in[0];
    const int* ei = (const int*)d_in[1];
    const float* W1 = (const float*)d_in[2];
    const float* b1 = (const float*)d_in[3];
    const float* e1 = (const float*)d_in[4];
    const float* W2 = (const float*)d_in[5];
    const float* b2 = (const float*)d_in[6];
    const float* e2 = (const float*)d_in[7];
    const float* W3 = (const float*)d_in[8];
    const float* b3 = (const float*)d_in[9];
    const float* e3 = (const float*)d_in[10];
    float* out = (float*)d_out;
    float* out_logits = out;
    float* out_probs = out + (size_t)N_NODES * 512;

    // workspace layout (~115 MB)
    char* ws = (char*)d_ws;
    int* rowptr = (int*)ws;                          // 50048 ints
    int* cursor = rowptr + 50048;                    // 50048 ints
    int* csr = cursor + 50048;                       // 800000 ints
    int* bsum = csr + N_EDGES;                       // 256 ints
    int* bpre = bsum + 256;                          // 256 ints
    unsigned short* Wsp = (unsigned short*)(bpre + 256);
    unsigned short* fa = Wsp + 3 * 524288;           // feature ping (51.2 MB)
    unsigned short* fb = fa + (size_t)N_NODES * 512; // feature pong (51.2 MB)

    // CSR build
    zero_k<<<196, 256, 0, stream>>>(cursor, N_NODES);
    count_k<<<(N_EDGES + 255) / 256, 256, 0, stream>>>(ei, cursor);
    blocksum_k<<<NB, 256, 0, stream>>>(cursor, bsum);
    bscan_k<<<1, 256, 0, stream>>>(bsum, bpre, rowptr);
    scatter_k<<<NB, 256, 0, stream>>>(cursor, bpre, rowptr);
    fill_k<<<(N_EDGES + 255) / 256, 256, 0, stream>>>(ei, cursor, csr);

    // weight prep (hi/lo bf16, transposed to [n][k])
    wprep_k<<<64, 256, 0, stream>>>(W1, Wsp,           Wsp + 262144);
    wprep_k<<<64, 256, 0, stream>>>(W2, Wsp + 524288,  Wsp + 786432);
    wprep_k<<<64, 256, 0, stream>>>(W3, Wsp + 1048576, Wsp + 1310720);

    // x -> bf16
    xconv_k<<<25000, 256, 0, stream>>>((const float4*)x, (uint2*)fa);

    const int GG = 4 * ((N_NODES + 127) / 128);  // 1564 blocks, 1D

    // layer 1: Y1 = X@W1 ; g1 = l2norm(relu(aggregate(Y1) + b1))
    gemm_k<false, false><<<GG, 256, 0, stream>>>(fa, Wsp, Wsp + 262144, nullptr, fb, nullptr, N_NODES);
    agg_k<true><<<12500, 256, 0, stream>>>((const uint4*)fb, rowptr, csr, e1, b1, (uint4*)fa);
    // layer 2: Y2 = g1@W2 ; g2 = l2norm(relu(aggregate(Y2) + b2))
    gemm_k<false, false><<<GG, 256, 0, stream>>>(fa, Wsp + 524288, Wsp + 786432, nullptr, fb, nullptr, N_NODES);
    agg_k<true><<<12500, 256, 0, stream>>>((const uint4*)fb, rowptr, csr, e2, b2, (uint4*)fa);
    // layer 3: s3 = aggregate(g2) ; logits = relu(s3@W3 + b3)  (split-precision W3)
    agg_k<false><<<12500, 256, 0, stream>>>((const uint4*)fa, rowptr, csr, e3, nullptr, (uint4*)fb);
    gemm_k<true, true><<<GG, 256, 0, stream>>>(fb, Wsp + 1048576, Wsp + 1310720, b3, nullptr, out_logits, N_NODES);
    // softmax -> probs
    softmax_k<<<N_NODES / 4, 256, 0, stream>>>(out_logits, out_probs);
}